// Round 2
// baseline (1688.634 us; speedup 1.0000x reference)
//
#include <hip/hip_runtime.h>
#include <math.h>

// ---------------------------------------------------------------------------
// Fused masked-attention baseline (all fp32, vector ALU):
//   qkv = x @ W^T + b          (GEMM, TRANSB, bias)     -> d_ws
//   s   = q @ k^T / 32         (GEMM, TRANSB, scale)    -> d_out.w region
//   w   = softmax(s)           (row softmax, in-place)
//   out = w @ v                (GEMM, no trans)         -> d_out.out region
// d_out layout (return order (out, w)): out [4,2048,1024] then w [4,2048,2048]
// ---------------------------------------------------------------------------

#define TILE 64
#define KT 16

template <bool TRANSB, bool BIAS>
__global__ __launch_bounds__(256) void gemm_kernel(
    const float* __restrict__ A, const float* __restrict__ B,
    const float* __restrict__ bias, float* __restrict__ C,
    int M, int N, int K, float scale,
    int lda, int ldb, int ldc,
    long batchStrideA, long batchStrideB, long batchStrideC)
{
    A += (long)blockIdx.z * batchStrideA;
    B += (long)blockIdx.z * batchStrideB;
    C += (long)blockIdx.z * batchStrideC;

    __shared__ float As[KT][TILE + 4];
    __shared__ float Bs[KT][TILE + 4];

    const int tx = threadIdx.x;            // 0..15 -> N dim
    const int ty = threadIdx.y;            // 0..15 -> M dim
    const int tid = ty * 16 + tx;

    const int row0 = blockIdx.y * TILE;    // M
    const int col0 = blockIdx.x * TILE;    // N

    float acc[4][4] = {};

    for (int k0 = 0; k0 < K; k0 += KT) {
        // ---- stage A tile: 64 rows x 16 k (store transposed As[kk][row]) ----
        {
            const int r  = tid >> 2;            // 0..63
            const int kk = (tid & 3) * 4;       // 0,4,8,12
            const float4 a4 =
                *(const float4*)(A + (long)(row0 + r) * lda + k0 + kk);
            As[kk + 0][r] = a4.x;
            As[kk + 1][r] = a4.y;
            As[kk + 2][r] = a4.z;
            As[kk + 3][r] = a4.w;
        }
        // ---- stage B tile ----
        if (TRANSB) {
            // B is [N,K] row-major; want Bs[kk][n]
            const int n  = tid >> 2;
            const int kk = (tid & 3) * 4;
            const float4 b4 =
                *(const float4*)(B + (long)(col0 + n) * ldb + k0 + kk);
            Bs[kk + 0][n] = b4.x;
            Bs[kk + 1][n] = b4.y;
            Bs[kk + 2][n] = b4.z;
            Bs[kk + 3][n] = b4.w;
        } else {
            // B is [K,N] row-major; want Bs[kk][n] (contiguous along n)
            const int n4 = (tid & 15) * 4;
            const int kk = tid >> 4;
            const float4 b4 =
                *(const float4*)(B + (long)(k0 + kk) * ldb + col0 + n4);
            *(float4*)&Bs[kk][n4] = b4;
        }
        __syncthreads();

        #pragma unroll
        for (int kk = 0; kk < KT; ++kk) {
            // contiguous aligned runs -> ds_read_b128 (2 reads instead of 8)
            const float4 a4 = *(const float4*)&As[kk][ty * 4];
            const float4 b4 = *(const float4*)&Bs[kk][tx * 4];
            const float a[4] = {a4.x, a4.y, a4.z, a4.w};
            const float b[4] = {b4.x, b4.y, b4.z, b4.w};
            #pragma unroll
            for (int i = 0; i < 4; ++i)
                #pragma unroll
                for (int j = 0; j < 4; ++j)
                    acc[i][j] = fmaf(a[i], b[j], acc[i][j]);
        }
        __syncthreads();
    }

    #pragma unroll
    for (int i = 0; i < 4; ++i) {
        const int r = row0 + ty * 4 + i;
        #pragma unroll
        for (int j = 0; j < 4; ++j) {
            const int c = col0 + tx * 4 + j;
            float v = acc[i][j] * scale;
            if (BIAS) v += bias[c];
            C[(long)r * ldc + c] = v;
        }
    }
}

// One block (256 threads) per row of 2048; row kept in registers (8/thread).
__global__ __launch_bounds__(256) void softmax_kernel(float* __restrict__ w)
{
    const long row = blockIdx.x;
    float* p = w + row * 2048;
    const int tid = threadIdx.x;

    float v[8];
    float m = -INFINITY;
    #pragma unroll
    for (int i = 0; i < 8; ++i) {
        v[i] = p[tid + i * 256];
        m = fmaxf(m, v[i]);
    }
    #pragma unroll
    for (int off = 32; off > 0; off >>= 1)
        m = fmaxf(m, __shfl_xor(m, off));

    __shared__ float redm[4];
    __shared__ float reds[4];
    const int wave = tid >> 6;
    if ((tid & 63) == 0) redm[wave] = m;
    __syncthreads();
    m = fmaxf(fmaxf(redm[0], redm[1]), fmaxf(redm[2], redm[3]));

    float s = 0.f;
    #pragma unroll
    for (int i = 0; i < 8; ++i) {
        v[i] = __expf(v[i] - m);
        s += v[i];
    }
    #pragma unroll
    for (int off = 32; off > 0; off >>= 1)
        s += __shfl_xor(s, off);
    if ((tid & 63) == 0) reds[wave] = s;
    __syncthreads();
    s = reds[0] + reds[1] + reds[2] + reds[3];

    const float inv = 1.0f / s;
    #pragma unroll
    for (int i = 0; i < 8; ++i)
        p[tid + i * 256] = v[i] * inv;
}

extern "C" void kernel_launch(void* const* d_in, const int* in_sizes, int n_in,
                              void* d_out, int out_size, void* d_ws, size_t ws_size,
                              hipStream_t stream)
{
    constexpr int B = 4, S = 2048, D = 1024;
    constexpr long BS = (long)B * S;             // 8192

    const float* x  = (const float*)d_in[0];     // [B,S,D]
    const float* W  = (const float*)d_in[1];     // [3D,D]
    const float* bq = (const float*)d_in[2];     // [3D]

    float* out = (float*)d_out;                  // [B,S,D]
    float* w   = out + BS * D;                   // [B,S,S]
    float* qkv = (float*)d_ws;                   // [B,S,3D]

    const dim3 blk(16, 16);

    // 1) qkv = x @ W^T + b     (M=8192, N=3072, K=1024)
    gemm_kernel<true, true><<<dim3(3 * D / TILE, BS / TILE, 1), blk, 0, stream>>>(
        x, W, bq, qkv, (int)BS, 3 * D, D, 1.0f,
        D, D, 3 * D, 0, 0, 0);

    // 2) scores = q @ k^T / 32 (per batch: M=N=2048, K=1024) -> w region
    gemm_kernel<true, false><<<dim3(S / TILE, S / TILE, B), blk, 0, stream>>>(
        qkv + 0, qkv + D, nullptr, w, S, S, D, 1.0f / 32.0f,
        3 * D, 3 * D, S,
        (long)S * 3 * D, (long)S * 3 * D, (long)S * S);

    // 3) softmax rows of w in-place
    softmax_kernel<<<(int)BS, 256, 0, stream>>>(w);

    // 4) out = w @ v           (per batch: M=2048, N=1024, K=2048)
    gemm_kernel<false, false><<<dim3(D / TILE, S / TILE, B), blk, 0, stream>>>(
        w, qkv + 2 * D, nullptr, out, S, D, S, 1.0f,
        S, 3 * D, D,
        (long)S * S, (long)S * 3 * D, (long)S * D);
}

// Round 3
// 743.126 us; speedup vs baseline: 2.2723x; 2.2723x over previous
//
#include <hip/hip_runtime.h>
#include <math.h>

// ---------------------------------------------------------------------------
// Masked attention via split-bf16 MFMA GEMMs (fp32 in/out, fp32 accumulate):
//   a = a_hi + a_lo (bf16 planes); a*b ~= ah*bh + ah*bl + al*bh  (3x MFMA)
//   qkv = x @ W^T + b        -> d_ws
//   s   = q @ k^T / 32       -> w region of d_out
//   w   = softmax(s)            in-place
//   out = w @ v              -> out region of d_out
// d_out layout: out [4,2048,1024] then w [4,2048,2048]
// ---------------------------------------------------------------------------

#define BM 128
#define BN 128
#define BK 32

using bfrag = __attribute__((ext_vector_type(8))) short;   // 8 bf16 = 4 VGPR
using f32x4 = __attribute__((ext_vector_type(4))) float;   // MFMA C/D

// pack top-16-bits (bf16 truncation) of two fp32 into one dword
__device__ __forceinline__ unsigned pack_hi16(unsigned u0, unsigned u1) {
    // result bytes (LE): [u0.b2, u0.b3, u1.b2, u1.b3]
    return __builtin_amdgcn_perm(u1, u0, 0x07060302u);
}

// split 8 consecutive fp32 into 4 hi-dwords + 4 lo-dwords (8 bf16 each)
__device__ __forceinline__ void split8(const float* f, unsigned* h, unsigned* l) {
    #pragma unroll
    for (int i = 0; i < 4; ++i) {
        const unsigned u0 = __float_as_uint(f[2 * i]);
        const unsigned u1 = __float_as_uint(f[2 * i + 1]);
        h[i] = pack_hi16(u0, u1);
        const float hf0 = __uint_as_float(u0 & 0xffff0000u);
        const float hf1 = __uint_as_float(u1 & 0xffff0000u);
        const unsigned v0 = __float_as_uint(f[2 * i] - hf0);
        const unsigned v1 = __float_as_uint(f[2 * i + 1] - hf1);
        l[i] = pack_hi16(v0, v1);
    }
}

template <bool TRANSB, bool BIAS>
__global__ __launch_bounds__(256, 2) void gemm_mfma(
    const float* __restrict__ A, const float* __restrict__ Bm,
    const float* __restrict__ bias, float* __restrict__ C,
    int K, float scale, int lda, int ldb, int ldc,
    long bsA, long bsB, long bsC)
{
    A  += (long)blockIdx.z * bsA;
    Bm += (long)blockIdx.z * bsB;
    C  += (long)blockIdx.z * bsC;

    // k-blocked LDS: elem k = kg*8 + j of the 32-chunk lives at [kg][row][j].
    // Writes are lane-contiguous 16B, fragment reads are 256B runs: conflict-free.
    __shared__ short As_hi[4][BM][8], As_lo[4][BM][8];
    __shared__ short Bs_hi[4][BN][8], Bs_lo[4][BN][8];

    const int tid  = threadIdx.x;
    const int lane = tid & 63;
    const int wave = tid >> 6;
    const int wr = wave >> 1, wc = wave & 1;      // 2x2 waves over 128x128

    const int row0 = blockIdx.y * BM;
    const int col0 = blockIdx.x * BN;

    // staging: thread owns 16 consecutive k at one row/col of the tile
    const int sr = tid & 127;                     // tile row (A) / tile col (B)
    const int skw = tid >> 7;                     // 0/1 -> k offset 0/16
    const int sk = skw * 16;
    const int kgw = skw * 2;                      // first kg this thread writes

    f32x4 acc[4][4];
    const f32x4 fzero = {0.f, 0.f, 0.f, 0.f};
    #pragma unroll
    for (int i = 0; i < 4; ++i)
        #pragma unroll
        for (int j = 0; j < 4; ++j) acc[i][j] = fzero;

    for (int k0 = 0; k0 < K; k0 += BK) {
        // ---- stage A (row-major, k contiguous) ----
        {
            const float* src = A + (long)(row0 + sr) * lda + k0 + sk;
            float f[16];
            *(float4*)&f[0]  = *(const float4*)(src + 0);
            *(float4*)&f[4]  = *(const float4*)(src + 4);
            *(float4*)&f[8]  = *(const float4*)(src + 8);
            *(float4*)&f[12] = *(const float4*)(src + 12);
            unsigned h[8], l[8];
            split8(f, h, l);
            split8(f + 8, h + 4, l + 4);
            *(uint4*)&As_hi[kgw][sr][0]     = make_uint4(h[0], h[1], h[2], h[3]);
            *(uint4*)&As_hi[kgw + 1][sr][0] = make_uint4(h[4], h[5], h[6], h[7]);
            *(uint4*)&As_lo[kgw][sr][0]     = make_uint4(l[0], l[1], l[2], l[3]);
            *(uint4*)&As_lo[kgw + 1][sr][0] = make_uint4(l[4], l[5], l[6], l[7]);
        }
        // ---- stage B ----
        {
            float f[16];
            if (TRANSB) {
                // B[n][k] row-major: k contiguous
                const float* src = Bm + (long)(col0 + sr) * ldb + k0 + sk;
                *(float4*)&f[0]  = *(const float4*)(src + 0);
                *(float4*)&f[4]  = *(const float4*)(src + 4);
                *(float4*)&f[8]  = *(const float4*)(src + 8);
                *(float4*)&f[12] = *(const float4*)(src + 12);
            } else {
                // B[k][n] row-major: gather a column segment (coalesced across lanes)
                const float* src = Bm + (long)(k0 + sk) * ldb + col0 + sr;
                #pragma unroll
                for (int j = 0; j < 16; ++j) f[j] = src[(long)j * ldb];
            }
            unsigned h[8], l[8];
            split8(f, h, l);
            split8(f + 8, h + 4, l + 4);
            *(uint4*)&Bs_hi[kgw][sr][0]     = make_uint4(h[0], h[1], h[2], h[3]);
            *(uint4*)&Bs_hi[kgw + 1][sr][0] = make_uint4(h[4], h[5], h[6], h[7]);
            *(uint4*)&Bs_lo[kgw][sr][0]     = make_uint4(l[0], l[1], l[2], l[3]);
            *(uint4*)&Bs_lo[kgw + 1][sr][0] = make_uint4(l[4], l[5], l[6], l[7]);
        }
        __syncthreads();

        // ---- fragments + 3-pass MFMA ----
        // A-frag: lane holds A[mi*16 + (lane&15)][(lane>>4)*8 + 0..7]
        // B-frag: lane holds B[(lane>>4)*8 + 0..7][nj*16 + (lane&15)]
        const int kg = lane >> 4;
        const int arow = wr * 64 + (lane & 15);
        const int bcol = wc * 64 + (lane & 15);

        bfrag ah[4], al[4], bh[4], bl[4];
        #pragma unroll
        for (int mi = 0; mi < 4; ++mi) {
            ah[mi] = *(bfrag*)&As_hi[kg][arow + mi * 16][0];
            al[mi] = *(bfrag*)&As_lo[kg][arow + mi * 16][0];
        }
        #pragma unroll
        for (int nj = 0; nj < 4; ++nj) {
            bh[nj] = *(bfrag*)&Bs_hi[kg][bcol + nj * 16][0];
            bl[nj] = *(bfrag*)&Bs_lo[kg][bcol + nj * 16][0];
        }
        #pragma unroll
        for (int mi = 0; mi < 4; ++mi)
            #pragma unroll
            for (int nj = 0; nj < 4; ++nj) {
                acc[mi][nj] = __builtin_amdgcn_mfma_f32_16x16x32_bf16(
                    ah[mi], bh[nj], acc[mi][nj], 0, 0, 0);
                acc[mi][nj] = __builtin_amdgcn_mfma_f32_16x16x32_bf16(
                    ah[mi], bl[nj], acc[mi][nj], 0, 0, 0);
                acc[mi][nj] = __builtin_amdgcn_mfma_f32_16x16x32_bf16(
                    al[mi], bh[nj], acc[mi][nj], 0, 0, 0);
            }
        __syncthreads();
    }

    // ---- epilogue: C/D layout col=lane&15, row=(lane>>4)*4+r ----
    #pragma unroll
    for (int nj = 0; nj < 4; ++nj) {
        const int c = col0 + wc * 64 + nj * 16 + (lane & 15);
        const float bv = BIAS ? bias[c] : 0.0f;
        #pragma unroll
        for (int mi = 0; mi < 4; ++mi) {
            const int rbase = row0 + wr * 64 + mi * 16 + (lane >> 4) * 4;
            #pragma unroll
            for (int r = 0; r < 4; ++r)
                C[(long)(rbase + r) * ldc + c] = acc[mi][nj][r] * scale + bv;
        }
    }
}

// One block (256 threads) per row of 2048; row kept in registers (8/thread).
__global__ __launch_bounds__(256) void softmax_kernel(float* __restrict__ w)
{
    const long row = blockIdx.x;
    float* p = w + row * 2048;
    const int tid = threadIdx.x;

    float v[8];
    float m = -INFINITY;
    #pragma unroll
    for (int i = 0; i < 8; ++i) {
        v[i] = p[tid + i * 256];
        m = fmaxf(m, v[i]);
    }
    #pragma unroll
    for (int off = 32; off > 0; off >>= 1)
        m = fmaxf(m, __shfl_xor(m, off));

    __shared__ float redm[4];
    __shared__ float reds[4];
    const int wave = tid >> 6;
    if ((tid & 63) == 0) redm[wave] = m;
    __syncthreads();
    m = fmaxf(fmaxf(redm[0], redm[1]), fmaxf(redm[2], redm[3]));

    float s = 0.f;
    #pragma unroll
    for (int i = 0; i < 8; ++i) {
        v[i] = __expf(v[i] - m);
        s += v[i];
    }
    #pragma unroll
    for (int off = 32; off > 0; off >>= 1)
        s += __shfl_xor(s, off);
    if ((tid & 63) == 0) reds[wave] = s;
    __syncthreads();
    s = reds[0] + reds[1] + reds[2] + reds[3];

    const float inv = 1.0f / s;
    #pragma unroll
    for (int i = 0; i < 8; ++i)
        p[tid + i * 256] = v[i] * inv;
}

extern "C" void kernel_launch(void* const* d_in, const int* in_sizes, int n_in,
                              void* d_out, int out_size, void* d_ws, size_t ws_size,
                              hipStream_t stream)
{
    constexpr int B = 4, S = 2048, D = 1024;
    constexpr long BS = (long)B * S;             // 8192

    const float* x  = (const float*)d_in[0];     // [B,S,D]
    const float* W  = (const float*)d_in[1];     // [3D,D]
    const float* bq = (const float*)d_in[2];     // [3D]

    float* out = (float*)d_out;                  // [B,S,D]
    float* w   = out + BS * D;                   // [B,S,S]
    float* qkv = (float*)d_ws;                   // [B,S,3D]

    // 1) qkv = x @ W^T + b     (M=8192, N=3072, K=1024)
    gemm_mfma<true, true><<<dim3(3 * D / BN, BS / BM, 1), 256, 0, stream>>>(
        x, W, bq, qkv, D, 1.0f,
        D, D, 3 * D, 0, 0, 0);

    // 2) scores = q @ k^T / 32 (per batch: M=N=2048, K=1024) -> w region
    gemm_mfma<true, false><<<dim3(S / BN, S / BM, B), 256, 0, stream>>>(
        qkv + 0, qkv + D, nullptr, w, D, 1.0f / 32.0f,
        3 * D, 3 * D, S,
        (long)S * 3 * D, (long)S * 3 * D, (long)S * S);

    // 3) softmax rows of w in-place
    softmax_kernel<<<(int)BS, 256, 0, stream>>>(w);

    // 4) out = w @ v           (per batch: M=2048, N=1024, K=2048)
    gemm_mfma<false, false><<<dim3(D / BN, S / BM, B), 256, 0, stream>>>(
        w, qkv + 2 * D, nullptr, out, S, 1.0f,
        S, 3 * D, D,
        (long)S * S, (long)S * 3 * D, (long)S * D);
}

// Round 6
// 549.545 us; speedup vs baseline: 3.0728x; 1.3523x over previous
//
#include <hip/hip_runtime.h>
#include <math.h>

// ---------------------------------------------------------------------------
// Masked attention, split-bf16 MFMA with pre-split planes + global_load_lds.
//   convert: x,W -> hi/lo bf16 planes      (scratch in w region of d_out)
//   GEMM1:   planes -> q/k/v hi/lo planes  (bias fused; v planes -> out region)
//   transp:  v planes -> vT planes          (ws)
//   GEMM2:   q,k planes -> scores fp32 (w region, overwrites scratch)
//   softmax: in-place on w
//   GEMM4:   A=w fp32 (reg-split), B=vT planes -> out
// All MFMA operands are [dim][k] bf16 planes; a*b ~= ah*bh + ah*bl + al*bh.
// LDS layout: [row][32] bf16 rows of 64B, slot-swizzled: slot' = kg ^ ((row>>1)&3)
// (global source pre-swizzled so global_load_lds's linear write lands swizzled).
// ---------------------------------------------------------------------------

typedef unsigned short u16;
using bfrag = __attribute__((ext_vector_type(8))) short;
using f32x4 = __attribute__((ext_vector_type(4))) float;

#define BM 128
#define BN 128
#define BK 32

// pack top-16-bits (bf16 truncation) of two fp32 into one dword
__device__ __forceinline__ unsigned pack_hi16(unsigned u0, unsigned u1) {
    return __builtin_amdgcn_perm(u1, u0, 0x07060302u);
}

// split 8 consecutive fp32 into 4 hi-dwords + 4 lo-dwords (2 bf16 each)
__device__ __forceinline__ void split8(const float* f, unsigned* h, unsigned* l) {
    #pragma unroll
    for (int i = 0; i < 4; ++i) {
        const unsigned u0 = __float_as_uint(f[2 * i]);
        const unsigned u1 = __float_as_uint(f[2 * i + 1]);
        h[i] = pack_hi16(u0, u1);
        const float hf0 = __uint_as_float(u0 & 0xffff0000u);
        const float hf1 = __uint_as_float(u1 & 0xffff0000u);
        const unsigned v0 = __float_as_uint(f[2 * i] - hf0);
        const unsigned v1 = __float_as_uint(f[2 * i + 1] - hf1);
        l[i] = pack_hi16(v0, v1);
    }
}

__device__ __forceinline__ void g2lds16(const u16* g, short* l) {
    __builtin_amdgcn_global_load_lds(
        (const __attribute__((address_space(1))) void*)g,
        (__attribute__((address_space(3))) void*)l,
        16, 0, 0);
}

// stage one 128x32 bf16 plane tile, global -> LDS, pre-swizzled source.
// LDS linear dest; data for (row, slot) comes from k-group g = slot ^ ((row>>1)&3).
__device__ __forceinline__ void load_plane(
    const u16* __restrict__ g, long ld, short* l, int wave, int lane)
{
    #pragma unroll
    for (int t = 0; t < 2; ++t) {
        const int chunk = wave * 2 + t;           // 0..7, uniform per wave
        const int row = chunk * 16 + (lane >> 2); // 0..127
        const int g8 = ((lane & 3) ^ ((row >> 1) & 3)) << 3;
        g2lds16(g + (long)row * ld + g8, l + chunk * 512);
    }
}

// read an 8-elem k-fragment for (row, kg) honoring the swizzle
__device__ __forceinline__ bfrag frag_ld(const short* plane, int row, int kg) {
    const int slot = kg ^ ((row >> 1) & 3);
    return *(const bfrag*)(plane + row * 32 + (slot << 3));
}

// ---------------------------------------------------------------------------
// convert fp32 -> hi/lo bf16 planes (flat)
__global__ __launch_bounds__(256) void convert_split(
    const float* __restrict__ in, u16* __restrict__ hi, u16* __restrict__ lo,
    long n8)
{
    const long i = (long)blockIdx.x * blockDim.x + threadIdx.x;
    if (i >= n8) return;
    float f[8];
    *(float4*)&f[0] = ((const float4*)in)[i * 2];
    *(float4*)&f[4] = ((const float4*)in)[i * 2 + 1];
    unsigned h[4], l[4];
    split8(f, h, l);
    *(uint4*)&hi[i * 8] = make_uint4(h[0], h[1], h[2], h[3]);
    *(uint4*)&lo[i * 8] = make_uint4(l[0], l[1], l[2], l[3]);
}

// ---------------------------------------------------------------------------
// transpose v planes [8192][1024] -> vT planes [1024][8192]
__global__ __launch_bounds__(256) void transpose_v(
    const u16* __restrict__ vh, const u16* __restrict__ vl,
    u16* __restrict__ vTh, u16* __restrict__ vTl)
{
    __shared__ u16 tile[64][72];
    const u16* __restrict__ src = blockIdx.z ? vl : vh;
    u16* __restrict__ dst       = blockIdx.z ? vTl : vTh;

    const int d0 = blockIdx.x * 64;
    const int s0 = blockIdx.y * 64;
    const int t = threadIdx.x;
    const int r = t >> 2, cseg = (t & 3) * 16;

    *(uint4*)&tile[r][cseg]     = *(const uint4*)&src[(long)(s0 + r) * 1024 + d0 + cseg];
    *(uint4*)&tile[r][cseg + 8] = *(const uint4*)&src[(long)(s0 + r) * 1024 + d0 + cseg + 8];
    __syncthreads();

    u16 tmp[16];
    #pragma unroll
    for (int j = 0; j < 16; ++j) tmp[j] = tile[cseg + j][r];
    *(uint4*)&dst[(long)(d0 + r) * 8192 + s0 + cseg]     = *(uint4*)&tmp[0];
    *(uint4*)&dst[(long)(d0 + r) * 8192 + s0 + cseg + 8] = *(uint4*)&tmp[8];
}

// ---------------------------------------------------------------------------
// plane GEMM: C[m][n] = sum_k A[m][k]*B[n][k], A/B given as hi/lo bf16 planes.
// EPI 0: C fp32 (*scale). EPI 1: split C(+bias) into q/k/v hi/lo planes.
template <int EPI>
__global__ __launch_bounds__(256) void gemm_planes(
    const u16* __restrict__ Ah_g, const u16* __restrict__ Al_g,
    const u16* __restrict__ Bh_g, const u16* __restrict__ Bl_g,
    const float* __restrict__ bias, float* __restrict__ C,
    u16* __restrict__ qh, u16* __restrict__ ql,
    u16* __restrict__ kh, u16* __restrict__ kl,
    u16* __restrict__ vh, u16* __restrict__ vl,
    int K, float scale, int lda, int ldb, int ldc,
    long bsA, long bsB, long bsC)
{
    Ah_g += (long)blockIdx.z * bsA;  Al_g += (long)blockIdx.z * bsA;
    Bh_g += (long)blockIdx.z * bsB;  Bl_g += (long)blockIdx.z * bsB;
    if (EPI == 0) C += (long)blockIdx.z * bsC;

    __shared__ __align__(16) short lds[4 * 4096];
    short* sAh = lds;
    short* sAl = lds + 4096;
    short* sBh = lds + 8192;
    short* sBl = lds + 12288;

    const int tid = threadIdx.x;
    const int lane = tid & 63;
    const int wave = tid >> 6;
    const int wr = wave >> 1, wc = wave & 1;

    const int row0 = blockIdx.y * BM;
    const int col0 = blockIdx.x * BN;

    f32x4 acc[4][4];
    const f32x4 fz = {0.f, 0.f, 0.f, 0.f};
    #pragma unroll
    for (int i = 0; i < 4; ++i)
        #pragma unroll
        for (int j = 0; j < 4; ++j) acc[i][j] = fz;

    const u16* At_h = Ah_g + (long)row0 * lda;
    const u16* At_l = Al_g + (long)row0 * lda;
    const u16* Bt_h = Bh_g + (long)col0 * ldb;
    const u16* Bt_l = Bl_g + (long)col0 * ldb;

    for (int k0 = 0; k0 < K; k0 += BK) {
        load_plane(At_h + k0, lda, sAh, wave, lane);
        load_plane(At_l + k0, lda, sAl, wave, lane);
        load_plane(Bt_h + k0, ldb, sBh, wave, lane);
        load_plane(Bt_l + k0, ldb, sBl, wave, lane);
        __syncthreads();

        const int kg = lane >> 4;
        const int arow = wr * 64 + (lane & 15);
        const int bcol = wc * 64 + (lane & 15);

        bfrag ah[4], al[4], bh[4], bl[4];
        #pragma unroll
        for (int mi = 0; mi < 4; ++mi) {
            ah[mi] = frag_ld(sAh, arow + mi * 16, kg);
            al[mi] = frag_ld(sAl, arow + mi * 16, kg);
        }
        #pragma unroll
        for (int nj = 0; nj < 4; ++nj) {
            bh[nj] = frag_ld(sBh, bcol + nj * 16, kg);
            bl[nj] = frag_ld(sBl, bcol + nj * 16, kg);
        }
        #pragma unroll
        for (int mi = 0; mi < 4; ++mi)
            #pragma unroll
            for (int nj = 0; nj < 4; ++nj) {
                acc[mi][nj] = __builtin_amdgcn_mfma_f32_16x16x32_bf16(
                    ah[mi], bh[nj], acc[mi][nj], 0, 0, 0);
                acc[mi][nj] = __builtin_amdgcn_mfma_f32_16x16x32_bf16(
                    ah[mi], bl[nj], acc[mi][nj], 0, 0, 0);
                acc[mi][nj] = __builtin_amdgcn_mfma_f32_16x16x32_bf16(
                    al[mi], bh[nj], acc[mi][nj], 0, 0, 0);
            }
        __syncthreads();
    }

    if (EPI == 0) {
        #pragma unroll
        for (int nj = 0; nj < 4; ++nj) {
            const int c = col0 + wc * 64 + nj * 16 + (lane & 15);
            #pragma unroll
            for (int mi = 0; mi < 4; ++mi) {
                const int rbase = row0 + wr * 64 + mi * 16 + (lane >> 4) * 4;
                #pragma unroll
                for (int r = 0; r < 4; ++r)
                    C[(long)(rbase + r) * ldc + c] = acc[mi][nj][r] * scale;
            }
        }
    } else {
        // split into q/k/v planes; block-uniform destination select
        u16 *ph, *pl;
        int coff;
        if (col0 >= 2048)      { ph = vh; pl = vl; coff = 2048; }
        else if (col0 >= 1024) { ph = kh; pl = kl; coff = 1024; }
        else                   { ph = qh; pl = ql; coff = 0; }
        #pragma unroll
        for (int nj = 0; nj < 4; ++nj) {
            const int c = col0 + wc * 64 + nj * 16 + (lane & 15);
            const float bv = bias[c];
            const int cl = c - coff;
            #pragma unroll
            for (int mi = 0; mi < 4; ++mi) {
                const int rbase = row0 + wr * 64 + mi * 16 + (lane >> 4) * 4;
                #pragma unroll
                for (int r = 0; r < 4; ++r) {
                    const float val = acc[mi][nj][r] + bv;
                    const unsigned u = __float_as_uint(val);
                    const float fh = __uint_as_float(u & 0xffff0000u);
                    const long idx = (long)(rbase + r) * 1024 + cl;
                    ph[idx] = (u16)(u >> 16);
                    pl[idx] = (u16)(__float_as_uint(val - fh) >> 16);
                }
            }
        }
    }
}

// ---------------------------------------------------------------------------
// GEMM4: C = A(fp32, reg-split) @ B(planes)^T-layout; C[m][n] += A[m][k]B[n][k]
__global__ __launch_bounds__(256) void gemm_wv(
    const float* __restrict__ A,
    const u16* __restrict__ Bh_g, const u16* __restrict__ Bl_g,
    float* __restrict__ C,
    int K, int lda, int ldb, int ldc, long bsA, long bsB, long bsC)
{
    A += (long)blockIdx.z * bsA;
    Bh_g += (long)blockIdx.z * bsB;  Bl_g += (long)blockIdx.z * bsB;
    C += (long)blockIdx.z * bsC;

    __shared__ __align__(16) short lds[4 * 4096];
    short* sAh = lds;
    short* sAl = lds + 4096;
    short* sBh = lds + 8192;
    short* sBl = lds + 12288;

    const int tid = threadIdx.x;
    const int lane = tid & 63;
    const int wave = tid >> 6;
    const int wr = wave >> 1, wc = wave & 1;

    const int row0 = blockIdx.y * BM;
    const int col0 = blockIdx.x * BN;

    // A staging ownership: row sr, k-half skw (16 elems)
    const int sr = tid & 127;
    const int skw = tid >> 7;
    const int kgw = skw * 2;
    const int ssw = (sr >> 1) & 3;

    f32x4 acc[4][4];
    const f32x4 fz = {0.f, 0.f, 0.f, 0.f};
    #pragma unroll
    for (int i = 0; i < 4; ++i)
        #pragma unroll
        for (int j = 0; j < 4; ++j) acc[i][j] = fz;

    const float* At = A + (long)(row0 + sr) * lda;
    const u16* Bt_h = Bh_g + (long)col0 * ldb;
    const u16* Bt_l = Bl_g + (long)col0 * ldb;

    for (int k0 = 0; k0 < K; k0 += BK) {
        // B planes: async direct to LDS
        load_plane(Bt_h + k0, ldb, sBh, wave, lane);
        load_plane(Bt_l + k0, ldb, sBl, wave, lane);
        // A: fp32 -> registers -> split -> swizzled LDS write
        {
            const float* src = At + k0 + skw * 16;
            float f[16];
            *(float4*)&f[0]  = *(const float4*)(src + 0);
            *(float4*)&f[4]  = *(const float4*)(src + 4);
            *(float4*)&f[8]  = *(const float4*)(src + 8);
            *(float4*)&f[12] = *(const float4*)(src + 12);
            unsigned h[8], l[8];
            split8(f, h, l);
            split8(f + 8, h + 4, l + 4);
            short* rh = sAh + sr * 32;
            short* rl = sAl + sr * 32;
            *(uint4*)(rh + (((kgw)     ^ ssw) << 3)) = make_uint4(h[0], h[1], h[2], h[3]);
            *(uint4*)(rh + (((kgw + 1) ^ ssw) << 3)) = make_uint4(h[4], h[5], h[6], h[7]);
            *(uint4*)(rl + (((kgw)     ^ ssw) << 3)) = make_uint4(l[0], l[1], l[2], l[3]);
            *(uint4*)(rl + (((kgw + 1) ^ ssw) << 3)) = make_uint4(l[4], l[5], l[6], l[7]);
        }
        __syncthreads();

        const int kg = lane >> 4;
        const int arow = wr * 64 + (lane & 15);
        const int bcol = wc * 64 + (lane & 15);

        bfrag ah[4], al[4], bh[4], bl[4];
        #pragma unroll
        for (int mi = 0; mi < 4; ++mi) {
            ah[mi] = frag_ld(sAh, arow + mi * 16, kg);
            al[mi] = frag_ld(sAl, arow + mi * 16, kg);
        }
        #pragma unroll
        for (int nj = 0; nj < 4; ++nj) {
            bh[nj] = frag_ld(sBh, bcol + nj * 16, kg);
            bl[nj] = frag_ld(sBl, bcol + nj * 16, kg);
        }
        #pragma unroll
        for (int mi = 0; mi < 4; ++mi)
            #pragma unroll
            for (int nj = 0; nj < 4; ++nj) {
                acc[mi][nj] = __builtin_amdgcn_mfma_f32_16x16x32_bf16(
                    ah[mi], bh[nj], acc[mi][nj], 0, 0, 0);
                acc[mi][nj] = __builtin_amdgcn_mfma_f32_16x16x32_bf16(
                    ah[mi], bl[nj], acc[mi][nj], 0, 0, 0);
                acc[mi][nj] = __builtin_amdgcn_mfma_f32_16x16x32_bf16(
                    al[mi], bh[nj], acc[mi][nj], 0, 0, 0);
            }
        __syncthreads();
    }

    #pragma unroll
    for (int nj = 0; nj < 4; ++nj) {
        const int c = col0 + wc * 64 + nj * 16 + (lane & 15);
        #pragma unroll
        for (int mi = 0; mi < 4; ++mi) {
            const int rbase = row0 + wr * 64 + mi * 16 + (lane >> 4) * 4;
            #pragma unroll
            for (int r = 0; r < 4; ++r)
                C[(long)(rbase + r) * ldc + c] = acc[mi][nj][r];
        }
    }
}

// ---------------------------------------------------------------------------
// row softmax, one block per row of 2048
__global__ __launch_bounds__(256) void softmax_kernel(float* __restrict__ w)
{
    const long row = blockIdx.x;
    float* p = w + row * 2048;
    const int tid = threadIdx.x;

    float v[8];
    float m = -INFINITY;
    #pragma unroll
    for (int i = 0; i < 8; ++i) {
        v[i] = p[tid + i * 256];
        m = fmaxf(m, v[i]);
    }
    #pragma unroll
    for (int off = 32; off > 0; off >>= 1)
        m = fmaxf(m, __shfl_xor(m, off));

    __shared__ float redm[4];
    __shared__ float reds[4];
    const int wave = tid >> 6;
    if ((tid & 63) == 0) redm[wave] = m;
    __syncthreads();
    m = fmaxf(fmaxf(redm[0], redm[1]), fmaxf(redm[2], redm[3]));

    float s = 0.f;
    #pragma unroll
    for (int i = 0; i < 8; ++i) {
        v[i] = __expf(v[i] - m);
        s += v[i];
    }
    #pragma unroll
    for (int off = 32; off > 0; off >>= 1)
        s += __shfl_xor(s, off);
    if ((tid & 63) == 0) reds[wave] = s;
    __syncthreads();
    s = reds[0] + reds[1] + reds[2] + reds[3];

    const float inv = 1.0f / s;
    #pragma unroll
    for (int i = 0; i < 8; ++i)
        p[tid + i * 256] = v[i] * inv;
}

// ---------------------------------------------------------------------------
extern "C" void kernel_launch(void* const* d_in, const int* in_sizes, int n_in,
                              void* d_out, int out_size, void* d_ws, size_t ws_size,
                              hipStream_t stream)
{
    constexpr int B = 4, S = 2048, D = 1024;
    constexpr long BS = (long)B * S;          // 8192
    constexpr long P = BS * D;                // 8388608 elems per plane

    const float* x  = (const float*)d_in[0];  // [8192,1024]
    const float* W  = (const float*)d_in[1];  // [3072,1024]
    const float* bq = (const float*)d_in[2];  // [3072]

    float* out = (float*)d_out;               // [8192,1024] fp32
    float* w   = out + P;                     // [4,2048,2048] fp32

    // ws: q/k planes + vT planes (6 x 16.78 MB = 100.66 MB)
    u16* wsu = (u16*)d_ws;
    u16 *qh = wsu,       *ql = qh + P;
    u16 *kh = ql + P,    *kl = kh + P;
    u16 *vTh = kl + P,   *vTl = vTh + P;

    // scratch planes inside the (not yet written) w region: 46.1 MB < 67.1 MB
    u16* wscr = (u16*)w;
    u16 *xh = wscr,      *xl = xh + P;
    u16 *Wh = xl + P,    *Wl = Wh + 3 * D * D;

    // v planes (s-major) in the (not yet written) out region: exactly 33.55 MB
    u16 *vh = (u16*)out, *vl = vh + P;

    // 1) convert x, W to planes
    convert_split<<<dim3((unsigned)(P / 8 / 256)), 256, 0, stream>>>(x, xh, xl, P / 8);
    convert_split<<<dim3((unsigned)(3 * D * D / 8 / 256)), 256, 0, stream>>>(
        W, Wh, Wl, 3 * D * D / 8);

    // 2) GEMM1: qkv planes = split(x @ W^T + b)
    gemm_planes<1><<<dim3(3 * D / BN, BS / BM, 1), 256, 0, stream>>>(
        xh, xl, Wh, Wl, bq, nullptr,
        qh, ql, kh, kl, vh, vl,
        D, 1.0f, D, D, 0, 0, 0, 0);

    // 3) transpose v planes -> vT planes
    transpose_v<<<dim3(D / 64, BS / 64, 2), 256, 0, stream>>>(vh, vl, vTh, vTl);

    // 4) GEMM2: scores = q @ k^T / 32  (overwrites plane scratch in w region)
    gemm_planes<0><<<dim3(S / BN, S / BM, B), 256, 0, stream>>>(
        qh, ql, kh, kl, nullptr, w,
        nullptr, nullptr, nullptr, nullptr, nullptr, nullptr,
        D, 1.0f / 32.0f, D, D, S,
        (long)S * D, (long)S * D, (long)S * S);

    // 5) softmax rows of w in-place
    softmax_kernel<<<(int)BS, 256, 0, stream>>>(w);

    // 6) GEMM4: out = w @ v  (A = w fp32 reg-split, B = vT planes)
    gemm_wv<<<dim3(D / BN, S / BM, B), 256, 0, stream>>>(
        w, vTh, vTl, out,
        S, S, (int)BS, D,
        (long)S * S, (long)S, (long)S * D);
}